// Round 6
// baseline (468.376 us; speedup 1.0000x reference)
//
#include <hip/hip_runtime.h>
#include <hip/hip_bf16.h>

#define N_NODES 50000
#define N_EDGES 625000
#define IN_DIM  300
#define KPAD    320   // IN_DIM padded to multiple of 32
#define HID     128
#define NLAYERS 4

#define SB      256                            // scan block size
#define NCH     ((N_NODES + SB - 1) / SB)      // 196 chunks

typedef __hip_bfloat16 bf16;
typedef __attribute__((ext_vector_type(8))) short short8;   // 8 bf16 = 4 VGPRs
typedef __attribute__((ext_vector_type(4))) float f32x4;

__device__ inline short f2bf(float v) {
    bf16 t = __float2bfloat16(v);
    return *reinterpret_cast<short*>(&t);
}
__device__ inline unsigned short f2bfu(float v) {
    bf16 t = __float2bfloat16(v);
    return *reinterpret_cast<unsigned short*>(&t);
}
__device__ inline float bflo(unsigned v) { return __uint_as_float((v & 0xffffu) << 16); }
__device__ inline float bfhi(unsigned v) { return __uint_as_float(v & 0xffff0000u); }

// ---------------- degree histogram (int) ----------------
__global__ void k_deg(const int* __restrict__ dst, int* __restrict__ deg) {
    int stride = gridDim.x * blockDim.x;
    for (int e = blockIdx.x * blockDim.x + threadIdx.x; e < N_EDGES; e += stride)
        atomicAdd(&deg[dst[e]], 1);
}

// ---------------- hierarchical scan: deg -> exclusive prefix ----------------
__global__ void k_scan1(const int* __restrict__ deg, int* __restrict__ bsum) {
    const int i = blockIdx.x * SB + threadIdx.x;
    int v = (i < N_NODES) ? deg[i] : 0;
#pragma unroll
    for (int off = 32; off > 0; off >>= 1) v += __shfl_down(v, off);
    __shared__ int wsum[SB / 64];
    if ((threadIdx.x & 63) == 0) wsum[threadIdx.x >> 6] = v;
    __syncthreads();
    if (threadIdx.x == 0) {
        int s = 0;
#pragma unroll
        for (int w = 0; w < SB / 64; w++) s += wsum[w];
        bsum[blockIdx.x] = s;
    }
}

__global__ void k_scan2(const int* __restrict__ bsum, int* __restrict__ boff) {
    __shared__ int s[SB];
    const int t = threadIdx.x;
    int v = (t < NCH) ? bsum[t] : 0;
    s[t] = v;
    __syncthreads();
    for (int off = 1; off < SB; off <<= 1) {
        int u = (t >= off) ? s[t - off] : 0;
        __syncthreads();
        s[t] += u;
        __syncthreads();
    }
    if (t < NCH) boff[t] = s[t] - v;   // exclusive
}

__global__ void k_scan3(const int* __restrict__ deg, const int* __restrict__ boff,
                        int* __restrict__ rowcur) {
    __shared__ int s[SB];
    const int b = blockIdx.x, t = threadIdx.x;
    const int i = b * SB + t;
    int v = (i < N_NODES) ? deg[i] : 0;
    s[t] = v;
    __syncthreads();
    for (int off = 1; off < SB; off <<= 1) {
        int u = (t >= off) ? s[t - off] : 0;
        __syncthreads();
        s[t] += u;
        __syncthreads();
    }
    if (i < N_NODES) rowcur[i] = boff[b] + s[t] - v;   // exclusive
}

// ---------------- deg(int) -> 1/max(deg,1) (float, in place) ----------------
__global__ void k_invdeg(int* degbuf) {
    int i = blockIdx.x * blockDim.x + threadIdx.x;
    if (i < N_NODES) {
        int d = degbuf[i];
        float inv = 1.0f / (float)max(d, 1);
        ((float*)degbuf)[i] = inv;
    }
}

// ---------------- CSR fill ----------------
__global__ void k_fill(const int* __restrict__ src, const int* __restrict__ dst,
                       int* __restrict__ rowcur, int* __restrict__ csr_src) {
    int stride = gridDim.x * blockDim.x;
    for (int e = blockIdx.x * blockDim.x + threadIdx.x; e < N_EDGES; e += stride) {
        int d = dst[e];
        int pos = atomicAdd(&rowcur[d], 1);
        csr_src[pos] = src[e];
    }
}

// ---------------- Wl/Wr -> W^T bf16 ----------------
__global__ void k_wconv(const float* __restrict__ Wl, const float* __restrict__ Wr,
                        bf16* __restrict__ WlT, bf16* __restrict__ WrT) {
    int idx = blockIdx.x * 256 + threadIdx.x;
    if (idx >= NLAYERS * HID * HID) return;
    int l = idx / (HID * HID);
    int rem = idx - l * HID * HID;
    int k = rem >> 7;
    int f = rem & 127;
    size_t o = (size_t)l * HID * HID + (size_t)f * HID + k;
    WlT[o] = __float2bfloat16(Wl[idx]);
    WrT[o] = __float2bfloat16(Wr[idx]);
}

// ---------------- emb_W[300][128] -> embT[128][KPAD] bf16 (zero-padded K) ----------------
__global__ void k_wembT(const float* __restrict__ W, bf16* __restrict__ embT) {
    int idx = blockIdx.x * 256 + threadIdx.x;
    if (idx >= HID * KPAD) return;
    int f = idx / KPAD, k = idx - f * KPAD;
    float v = (k < IN_DIM) ? W[(size_t)k * HID + f] : 0.0f;
    embT[idx] = __float2bfloat16(v);
}

// ---------------- embedding via MFMA, column-split + 2-deep pipeline ----------------
// block = 64 rows x 64 cols; grid = 782*2
__global__ void k_embed_mfma(const float* __restrict__ x, const bf16* __restrict__ embT,
                             const float* __restrict__ b, bf16* __restrict__ h) {
    const int wid  = threadIdx.x >> 6;
    const int lane = threadIdx.x & 63;
    const int rblk = blockIdx.x >> 1;
    const int cb   = blockIdx.x & 1;        // column half: cols [cb*64, cb*64+64)
    const int r0   = rblk * 64 + wid * 16;
    const int lrow = lane & 15;
    const int kgrp = lane >> 4;

    const int arow = min(r0 + lrow, N_NODES - 1);
    const float* xrow = x + (size_t)arow * IN_DIM;

    f32x4 acc[4];
#pragma unroll
    for (int c = 0; c < 4; c++) acc[c] = (f32x4){0.f, 0.f, 0.f, 0.f};

    // prefetch kk = 0
    float4 f0 = *reinterpret_cast<const float4*>(xrow + kgrp * 8);
    float4 f1 = *reinterpret_cast<const float4*>(xrow + kgrp * 8 + 4);

    for (int kk = 0; kk < 9; kk++) {        // kk=0..8: all 8 floats valid (max 256+24+8=288<300... 296<=300)
        const int k0 = kk * 32 + kgrp * 8;
        float4 g0, g1;
        if (kk < 8) {                       // issue next-iteration loads early
            g0 = *reinterpret_cast<const float4*>(xrow + k0 + 32);
            g1 = *reinterpret_cast<const float4*>(xrow + k0 + 36);
        }
        short8 a;
        a[0] = f2bf(f0.x); a[1] = f2bf(f0.y); a[2] = f2bf(f0.z); a[3] = f2bf(f0.w);
        a[4] = f2bf(f1.x); a[5] = f2bf(f1.y); a[6] = f2bf(f1.z); a[7] = f2bf(f1.w);
#pragma unroll
        for (int c = 0; c < 4; c++) {
            short8 bfrag = *reinterpret_cast<const short8*>(
                embT + (size_t)(cb * 64 + c * 16 + lrow) * KPAD + k0);
            acc[c] = __builtin_amdgcn_mfma_f32_16x16x32_bf16(a, bfrag, acc[c], 0, 0, 0);
        }
        f0 = g0; f1 = g1;
    }
    {   // tail kk = 9: k0 = 288 + kgrp*8, mask k >= 300
        const int k0 = 9 * 32 + kgrp * 8;
        short8 a;
#pragma unroll
        for (int j = 0; j < 8; j++) {
            int k = k0 + j;
            a[j] = f2bf((k < IN_DIM) ? xrow[k] : 0.0f);
        }
#pragma unroll
        for (int c = 0; c < 4; c++) {
            short8 bfrag = *reinterpret_cast<const short8*>(
                embT + (size_t)(cb * 64 + c * 16 + lrow) * KPAD + k0);
            acc[c] = __builtin_amdgcn_mfma_f32_16x16x32_bf16(a, bfrag, acc[c], 0, 0, 0);
        }
    }

#pragma unroll
    for (int c = 0; c < 4; c++) {
        const int col = cb * 64 + c * 16 + lrow;
        const float bias = b[col];
#pragma unroll
        for (int r = 0; r < 4; r++) {
            const int row = r0 + kgrp * 4 + r;
            if (row < N_NODES)
                h[(size_t)row * HID + col] = __float2bfloat16(fmaxf(acc[c][r] + bias, 0.0f));
        }
    }
}

// ---------------- fused layer: gather -> LDS, then MFMA combine ----------------
// out = relu((mean_{src} h[src]) @ Wl + bl + h @ Wr);  h_out != h_in (no aliasing)
template<int STORE_F32>
__global__ void k_layer(const int* __restrict__ rowend, const int* __restrict__ csr_src,
                        const bf16* __restrict__ h_in, const float* __restrict__ invdeg,
                        const bf16* __restrict__ WlT, const bf16* __restrict__ WrT,
                        const float* __restrict__ bl, void* __restrict__ outp) {
    __shared__ bf16 aggs[64][HID];          // 16 KB
    const int wid  = threadIdx.x >> 6;
    const int lane = threadIdx.x & 63;
    const int half = lane >> 5;
    const int fl   = lane & 31;
    const int n0   = blockIdx.x * 64 + wid * 16;

    // ---- phase 1: gather 16 nodes per wave, half-wave per node (2 concurrent) ----
    for (int i = half; i < 16; i += 2) {
        const int node = n0 + i;
        float a0 = 0.f, a1 = 0.f, a2 = 0.f, a3 = 0.f;
        float b0 = 0.f, b1 = 0.f, b2 = 0.f, b3 = 0.f;
        if (node < N_NODES) {
            const int beg = (node == 0) ? 0 : rowend[node - 1];
            const int end = rowend[node];
            int e = beg;
            for (; e + 2 <= end; e += 2) {
                int s0 = csr_src[e];
                int s1 = csr_src[e + 1];
                uint2 v0 = *reinterpret_cast<const uint2*>(h_in + (size_t)s0 * HID + fl * 4);
                uint2 v1 = *reinterpret_cast<const uint2*>(h_in + (size_t)s1 * HID + fl * 4);
                a0 += bflo(v0.x); a1 += bfhi(v0.x); a2 += bflo(v0.y); a3 += bfhi(v0.y);
                b0 += bflo(v1.x); b1 += bfhi(v1.x); b2 += bflo(v1.y); b3 += bfhi(v1.y);
            }
            if (e < end) {
                int s = csr_src[e];
                uint2 v = *reinterpret_cast<const uint2*>(h_in + (size_t)s * HID + fl * 4);
                a0 += bflo(v.x); a1 += bfhi(v.x); a2 += bflo(v.y); a3 += bfhi(v.y);
            }
            const float id = invdeg[node];
            a0 = (a0 + b0) * id; a1 = (a1 + b1) * id;
            a2 = (a2 + b2) * id; a3 = (a3 + b3) * id;
        }
        uint2 o;
        o.x = (unsigned)f2bfu(a0) | ((unsigned)f2bfu(a1) << 16);
        o.y = (unsigned)f2bfu(a2) | ((unsigned)f2bfu(a3) << 16);
        *reinterpret_cast<uint2*>(&aggs[wid * 16 + i][fl * 4]) = o;
    }
    __syncthreads();

    // ---- phase 2: MFMA combine ----
    const int lrow = lane & 15;
    const int kgrp = lane >> 4;
    const int r0   = blockIdx.x * 64 + wid * 16;
    const int arow = min(r0 + lrow, N_NODES - 1);

    f32x4 acc[8];
#pragma unroll
    for (int c = 0; c < 8; c++) acc[c] = (f32x4){0.f, 0.f, 0.f, 0.f};

    // m = 0: A = agg (LDS), B = WlT
#pragma unroll
    for (int kk = 0; kk < 4; kk++) {
        const int k0 = kk * 32 + kgrp * 8;
        short8 a = *reinterpret_cast<const short8*>(&aggs[wid * 16 + lrow][k0]);
#pragma unroll
        for (int c = 0; c < 8; c++) {
            short8 b = *reinterpret_cast<const short8*>(WlT + (size_t)(c * 16 + lrow) * HID + k0);
            acc[c] = __builtin_amdgcn_mfma_f32_16x16x32_bf16(a, b, acc[c], 0, 0, 0);
        }
    }
    // m = 1: A = h_in (global), B = WrT
#pragma unroll
    for (int kk = 0; kk < 4; kk++) {
        const int k0 = kk * 32 + kgrp * 8;
        short8 a = *reinterpret_cast<const short8*>(h_in + (size_t)arow * HID + k0);
#pragma unroll
        for (int c = 0; c < 8; c++) {
            short8 b = *reinterpret_cast<const short8*>(WrT + (size_t)(c * 16 + lrow) * HID + k0);
            acc[c] = __builtin_amdgcn_mfma_f32_16x16x32_bf16(a, b, acc[c], 0, 0, 0);
        }
    }

#pragma unroll
    for (int c = 0; c < 8; c++) {
        const int col = c * 16 + lrow;
        const float bias = bl[col];
#pragma unroll
        for (int r = 0; r < 4; r++) {
            const int row = r0 + kgrp * 4 + r;
            if (row < N_NODES) {
                float v = fmaxf(acc[c][r] + bias, 0.0f);
                if (STORE_F32)
                    ((float*)outp)[(size_t)row * HID + col] = v;
                else
                    ((bf16*)outp)[(size_t)row * HID + col] = __float2bfloat16(v);
            }
        }
    }
}

extern "C" void kernel_launch(void* const* d_in, const int* in_sizes, int n_in,
                              void* d_out, int out_size, void* d_ws, size_t ws_size,
                              hipStream_t stream) {
    const float* x     = (const float*)d_in[0];
    const int*   ei    = (const int*)d_in[1];
    const float* emb_W = (const float*)d_in[2];
    const float* emb_b = (const float*)d_in[3];
    const float* Wl    = (const float*)d_in[4];
    const float* bl    = (const float*)d_in[5];
    const float* Wr    = (const float*)d_in[6];

    const int* src = ei;
    const int* dst = ei + N_EDGES;

    // workspace layout
    char* ws = (char*)d_ws;
    size_t o = 0;
    int*  degbuf = (int*)(ws + o);  o += ((size_t)N_NODES * 4 + 255) & ~(size_t)255;
    int*  rowcur = (int*)(ws + o);  o += ((size_t)N_NODES * 4 + 255) & ~(size_t)255;
    int*  csrsrc = (int*)(ws + o);  o += ((size_t)N_EDGES * 4 + 255) & ~(size_t)255;
    int*  bsum   = (int*)(ws + o);  o += ((size_t)NCH * 4 + 255) & ~(size_t)255;
    int*  boff   = (int*)(ws + o);  o += ((size_t)NCH * 4 + 255) & ~(size_t)255;
    bf16* WlT    = (bf16*)(ws + o); o += ((size_t)NLAYERS * HID * HID * 2 + 255) & ~(size_t)255;
    bf16* WrT    = (bf16*)(ws + o); o += ((size_t)NLAYERS * HID * HID * 2 + 255) & ~(size_t)255;
    bf16* embT   = (bf16*)(ws + o); o += ((size_t)HID * KPAD * 2 + 255) & ~(size_t)255;
    bf16* bufA   = (bf16*)(ws + o); o += ((size_t)N_NODES * HID * 2 + 255) & ~(size_t)255;
    bf16* bufB   = (bf16*)(ws + o);

    // ---- build CSR ----
    hipMemsetAsync(degbuf, 0, (size_t)N_NODES * sizeof(int), stream);
    k_deg<<<1024, 256, 0, stream>>>(dst, degbuf);
    k_scan1<<<NCH, SB, 0, stream>>>(degbuf, bsum);
    k_scan2<<<1, SB, 0, stream>>>(bsum, boff);
    k_scan3<<<NCH, SB, 0, stream>>>(degbuf, boff, rowcur);
    k_invdeg<<<(N_NODES + 255) / 256, 256, 0, stream>>>(degbuf);
    const float* invdeg = (const float*)degbuf;
    k_fill<<<1024, 256, 0, stream>>>(src, dst, rowcur, csrsrc);
    // rowcur[n] is now the END offset of row n

    // ---- weight prep ----
    k_wconv<<<(NLAYERS * HID * HID + 255) / 256, 256, 0, stream>>>(Wl, Wr, WlT, WrT);
    k_wembT<<<(HID * KPAD + 255) / 256, 256, 0, stream>>>(emb_W, embT);

    // ---- h0 = relu(x @ emb_W + emb_b) -> bufA (bf16), via MFMA ----
    const int rtiles = (N_NODES + 63) / 64;   // 782
    k_embed_mfma<<<rtiles * 2, 256, 0, stream>>>(x, embT, emb_b, bufA);

    // ---- 4 fused layers, ping-pong bufA <-> bufB ----
    for (int l = 0; l < NLAYERS; l++) {
        bf16* h_in  = (l & 1) ? bufB : bufA;
        bf16* h_out = (l & 1) ? bufA : bufB;
        const bf16* wlt = WlT + (size_t)l * HID * HID;
        const bf16* wrt = WrT + (size_t)l * HID * HID;
        const float* blp = bl + (size_t)l * HID;
        if (l == NLAYERS - 1)
            k_layer<1><<<rtiles, 256, 0, stream>>>(rowcur, csrsrc, h_in, invdeg, wlt, wrt, blp, d_out);
        else
            k_layer<0><<<rtiles, 256, 0, stream>>>(rowcur, csrsrc, h_in, invdeg, wlt, wrt, blp, h_out);
    }
}

// Round 7
// 396.238 us; speedup vs baseline: 1.1821x; 1.1821x over previous
//
#include <hip/hip_runtime.h>
#include <hip/hip_bf16.h>

#define N_NODES 50000
#define N_EDGES 625000
#define IN_DIM  300
#define KPAD    320   // IN_DIM padded to multiple of 32
#define HID     128
#define NLAYERS 4

#define SB      256                            // scan block size
#define NCH     ((N_NODES + SB - 1) / SB)      // 196 chunks

typedef __hip_bfloat16 bf16;
typedef __attribute__((ext_vector_type(8))) short short8;   // 8 bf16 = 4 VGPRs
typedef __attribute__((ext_vector_type(4))) float f32x4;

__device__ inline short f2bf(float v) {
    bf16 t = __float2bfloat16(v);
    return *reinterpret_cast<short*>(&t);
}
__device__ inline unsigned short f2bfu(float v) {
    bf16 t = __float2bfloat16(v);
    return *reinterpret_cast<unsigned short*>(&t);
}
__device__ inline float bflo(unsigned v) { return __uint_as_float((v & 0xffffu) << 16); }
__device__ inline float bfhi(unsigned v) { return __uint_as_float(v & 0xffff0000u); }

// ---------------- degree histogram (int) ----------------
__global__ void k_deg(const int* __restrict__ dst, int* __restrict__ deg) {
    int stride = gridDim.x * blockDim.x;
    for (int e = blockIdx.x * blockDim.x + threadIdx.x; e < N_EDGES; e += stride)
        atomicAdd(&deg[dst[e]], 1);
}

// ---------------- hierarchical scan: deg -> exclusive prefix ----------------
__global__ void k_scan1(const int* __restrict__ deg, int* __restrict__ bsum) {
    const int i = blockIdx.x * SB + threadIdx.x;
    int v = (i < N_NODES) ? deg[i] : 0;
#pragma unroll
    for (int off = 32; off > 0; off >>= 1) v += __shfl_down(v, off);
    __shared__ int wsum[SB / 64];
    if ((threadIdx.x & 63) == 0) wsum[threadIdx.x >> 6] = v;
    __syncthreads();
    if (threadIdx.x == 0) {
        int s = 0;
#pragma unroll
        for (int w = 0; w < SB / 64; w++) s += wsum[w];
        bsum[blockIdx.x] = s;
    }
}

__global__ void k_scan2(const int* __restrict__ bsum, int* __restrict__ boff) {
    __shared__ int s[SB];
    const int t = threadIdx.x;
    int v = (t < NCH) ? bsum[t] : 0;
    s[t] = v;
    __syncthreads();
    for (int off = 1; off < SB; off <<= 1) {
        int u = (t >= off) ? s[t - off] : 0;
        __syncthreads();
        s[t] += u;
        __syncthreads();
    }
    if (t < NCH) boff[t] = s[t] - v;   // exclusive
}

__global__ void k_scan3(const int* __restrict__ deg, const int* __restrict__ boff,
                        int* __restrict__ rowcur) {
    __shared__ int s[SB];
    const int b = blockIdx.x, t = threadIdx.x;
    const int i = b * SB + t;
    int v = (i < N_NODES) ? deg[i] : 0;
    s[t] = v;
    __syncthreads();
    for (int off = 1; off < SB; off <<= 1) {
        int u = (t >= off) ? s[t - off] : 0;
        __syncthreads();
        s[t] += u;
        __syncthreads();
    }
    if (i < N_NODES) rowcur[i] = boff[b] + s[t] - v;   // exclusive
}

// ---------------- deg(int) -> 1/max(deg,1) (float, in place) ----------------
__global__ void k_invdeg(int* degbuf) {
    int i = blockIdx.x * blockDim.x + threadIdx.x;
    if (i < N_NODES) {
        int d = degbuf[i];
        float inv = 1.0f / (float)max(d, 1);
        ((float*)degbuf)[i] = inv;
    }
}

// ---------------- CSR fill ----------------
__global__ void k_fill(const int* __restrict__ src, const int* __restrict__ dst,
                       int* __restrict__ rowcur, int* __restrict__ csr_src) {
    int stride = gridDim.x * blockDim.x;
    for (int e = blockIdx.x * blockDim.x + threadIdx.x; e < N_EDGES; e += stride) {
        int d = dst[e];
        int pos = atomicAdd(&rowcur[d], 1);
        csr_src[pos] = src[e];
    }
}

// ---------------- Wl/Wr -> W^T bf16 ----------------
__global__ void k_wconv(const float* __restrict__ Wl, const float* __restrict__ Wr,
                        bf16* __restrict__ WlT, bf16* __restrict__ WrT) {
    int idx = blockIdx.x * 256 + threadIdx.x;
    if (idx >= NLAYERS * HID * HID) return;
    int l = idx / (HID * HID);
    int rem = idx - l * HID * HID;
    int k = rem >> 7;
    int f = rem & 127;
    size_t o = (size_t)l * HID * HID + (size_t)f * HID + k;
    WlT[o] = __float2bfloat16(Wl[idx]);
    WrT[o] = __float2bfloat16(Wr[idx]);
}

// ---------------- emb_W[300][128] -> embT[128][KPAD] bf16 (zero-padded K) ----------------
__global__ void k_wembT(const float* __restrict__ W, bf16* __restrict__ embT) {
    int idx = blockIdx.x * 256 + threadIdx.x;
    if (idx >= HID * KPAD) return;
    int f = idx / KPAD, k = idx - f * KPAD;
    float v = (k < IN_DIM) ? W[(size_t)k * HID + f] : 0.0f;
    embT[idx] = __float2bfloat16(v);
}

// ---------------- embedding via MFMA (round-5 version, measured 54 us) ----------------
__global__ void k_embed_mfma(const float* __restrict__ x, const bf16* __restrict__ embT,
                             const float* __restrict__ b, bf16* __restrict__ h) {
    const int wid  = threadIdx.x >> 6;
    const int lane = threadIdx.x & 63;
    const int r0   = blockIdx.x * 64 + wid * 16;
    const int lrow = lane & 15;
    const int kgrp = lane >> 4;

    const int arow = min(r0 + lrow, N_NODES - 1);
    const float* xrow = x + (size_t)arow * IN_DIM;

    f32x4 acc[8];
#pragma unroll
    for (int c = 0; c < 8; c++) acc[c] = (f32x4){0.f, 0.f, 0.f, 0.f};

    for (int kk = 0; kk < KPAD / 32; kk++) {
        const int k0 = kk * 32 + kgrp * 8;
        short8 a;
        if (kk < 9) {
            float4 f0 = *reinterpret_cast<const float4*>(xrow + k0);
            float4 f1 = *reinterpret_cast<const float4*>(xrow + k0 + 4);
            a[0] = f2bf(f0.x); a[1] = f2bf(f0.y); a[2] = f2bf(f0.z); a[3] = f2bf(f0.w);
            a[4] = f2bf(f1.x); a[5] = f2bf(f1.y); a[6] = f2bf(f1.z); a[7] = f2bf(f1.w);
        } else {
#pragma unroll
            for (int j = 0; j < 8; j++) {
                int k = k0 + j;
                a[j] = f2bf((k < IN_DIM) ? xrow[k] : 0.0f);
            }
        }
#pragma unroll
        for (int c = 0; c < 8; c++) {
            short8 bfrag = *reinterpret_cast<const short8*>(embT + (size_t)(c * 16 + lrow) * KPAD + k0);
            acc[c] = __builtin_amdgcn_mfma_f32_16x16x32_bf16(a, bfrag, acc[c], 0, 0, 0);
        }
    }

#pragma unroll
    for (int c = 0; c < 8; c++) {
        const int col = c * 16 + lrow;
        const float bias = b[col];
#pragma unroll
        for (int r = 0; r < 4; r++) {
            const int row = r0 + kgrp * 4 + r;
            if (row < N_NODES)
                h[(size_t)row * HID + col] = __float2bfloat16(fmaxf(acc[c][r] + bias, 0.0f));
        }
    }
}

// ---------------- gather-aggregate: quarter-wave per edge, 16B/lane ----------------
// wave = 1 node; lane -> (group g = lane>>4 owns edge stream e+g, fl = lane&15 owns 16B chunk)
// one dwordx4 instruction fetches 4 edges' row-chunks; 2x unroll = 8 edges in flight.
__global__ void k_gather(const int* __restrict__ rowend, const int* __restrict__ csr_src,
                         const bf16* __restrict__ h, const float* __restrict__ invdeg,
                         bf16* __restrict__ agg) {
    const int node = blockIdx.x * (blockDim.x >> 6) + (threadIdx.x >> 6);
    if (node >= N_NODES) return;
    const int lane = threadIdx.x & 63;
    const int g    = lane >> 4;
    const int fl   = lane & 15;
    const int beg = (node == 0) ? 0 : rowend[node - 1];
    const int end = rowend[node];

    float a0 = 0.f, a1 = 0.f, a2 = 0.f, a3 = 0.f;
    float a4 = 0.f, a5 = 0.f, a6 = 0.f, a7 = 0.f;
    float c0 = 0.f, c1 = 0.f, c2 = 0.f, c3 = 0.f;
    float c4 = 0.f, c5 = 0.f, c6 = 0.f, c7 = 0.f;

    const bf16* hrowbase = h;   // row s: hrowbase + s*HID + fl*8

    int e = beg;
    for (; e + 8 <= end; e += 8) {
        int s0 = csr_src[e + g];
        int s1 = csr_src[e + 4 + g];
        uint4 v0 = *reinterpret_cast<const uint4*>(hrowbase + (size_t)s0 * HID + fl * 8);
        uint4 v1 = *reinterpret_cast<const uint4*>(hrowbase + (size_t)s1 * HID + fl * 8);
        a0 += bflo(v0.x); a1 += bfhi(v0.x); a2 += bflo(v0.y); a3 += bfhi(v0.y);
        a4 += bflo(v0.z); a5 += bfhi(v0.z); a6 += bflo(v0.w); a7 += bfhi(v0.w);
        c0 += bflo(v1.x); c1 += bfhi(v1.x); c2 += bflo(v1.y); c3 += bfhi(v1.y);
        c4 += bflo(v1.z); c5 += bfhi(v1.z); c6 += bflo(v1.w); c7 += bfhi(v1.w);
    }
    for (; e + 4 <= end; e += 4) {
        int s0 = csr_src[e + g];
        uint4 v0 = *reinterpret_cast<const uint4*>(hrowbase + (size_t)s0 * HID + fl * 8);
        a0 += bflo(v0.x); a1 += bfhi(v0.x); a2 += bflo(v0.y); a3 += bfhi(v0.y);
        a4 += bflo(v0.z); a5 += bfhi(v0.z); a6 += bflo(v0.w); a7 += bfhi(v0.w);
    }
    if (e < end) {                      // tail: 1..3 edges, per-group predicated
        int idx = e + g;
        bool valid = idx < end;
        int s = csr_src[valid ? idx : end - 1];
        uint4 v = *reinterpret_cast<const uint4*>(hrowbase + (size_t)s * HID + fl * 8);
        if (valid) {
            a0 += bflo(v.x); a1 += bfhi(v.x); a2 += bflo(v.y); a3 += bfhi(v.y);
            a4 += bflo(v.z); a5 += bfhi(v.z); a6 += bflo(v.w); a7 += bfhi(v.w);
        }
    }
    a0 += c0; a1 += c1; a2 += c2; a3 += c3;
    a4 += c4; a5 += c5; a6 += c6; a7 += c7;

    // reduce across the 4 groups (lanes differing in bits 4,5)
    a0 += __shfl_xor(a0, 16); a1 += __shfl_xor(a1, 16);
    a2 += __shfl_xor(a2, 16); a3 += __shfl_xor(a3, 16);
    a4 += __shfl_xor(a4, 16); a5 += __shfl_xor(a5, 16);
    a6 += __shfl_xor(a6, 16); a7 += __shfl_xor(a7, 16);
    a0 += __shfl_xor(a0, 32); a1 += __shfl_xor(a1, 32);
    a2 += __shfl_xor(a2, 32); a3 += __shfl_xor(a3, 32);
    a4 += __shfl_xor(a4, 32); a5 += __shfl_xor(a5, 32);
    a6 += __shfl_xor(a6, 32); a7 += __shfl_xor(a7, 32);

    if (g == 0) {
        const float id = invdeg[node];
        uint4 o;
        o.x = (unsigned)f2bfu(a0 * id) | ((unsigned)f2bfu(a1 * id) << 16);
        o.y = (unsigned)f2bfu(a2 * id) | ((unsigned)f2bfu(a3 * id) << 16);
        o.z = (unsigned)f2bfu(a4 * id) | ((unsigned)f2bfu(a5 * id) << 16);
        o.w = (unsigned)f2bfu(a6 * id) | ((unsigned)f2bfu(a7 * id) << 16);
        *reinterpret_cast<uint4*>(agg + (size_t)node * HID + fl * 8) = o;
    }
}

// ---------------- combine via MFMA: out = relu(agg @ Wl + bl + h_in @ Wr) ----------------
// h_out may alias agg: each wave reads only its own 16 rows before writing them.
template<int STORE_F32>
__global__ void k_combine_mfma(const bf16* __restrict__ agg, const bf16* __restrict__ h_in,
                               const bf16* __restrict__ WlT, const bf16* __restrict__ WrT,
                               const float* __restrict__ bl, void* __restrict__ outp) {
    const int wid  = threadIdx.x >> 6;
    const int lane = threadIdx.x & 63;
    const int r0   = blockIdx.x * 64 + wid * 16;
    const int lrow = lane & 15;
    const int kgrp = lane >> 4;

    f32x4 acc[8];
#pragma unroll
    for (int c = 0; c < 8; c++) acc[c] = (f32x4){0.f, 0.f, 0.f, 0.f};

    const int arow = min(r0 + lrow, N_NODES - 1);

#pragma unroll
    for (int m = 0; m < 2; m++) {
        const bf16* A  = m ? h_in : agg;
        const bf16* BT = m ? WrT  : WlT;
#pragma unroll
        for (int kk = 0; kk < 4; kk++) {
            const int k0 = kk * 32 + kgrp * 8;
            short8 a = *reinterpret_cast<const short8*>(A + (size_t)arow * HID + k0);
#pragma unroll
            for (int c = 0; c < 8; c++) {
                short8 b = *reinterpret_cast<const short8*>(BT + (size_t)(c * 16 + lrow) * HID + k0);
                acc[c] = __builtin_amdgcn_mfma_f32_16x16x32_bf16(a, b, acc[c], 0, 0, 0);
            }
        }
    }

#pragma unroll
    for (int c = 0; c < 8; c++) {
        const int col = c * 16 + lrow;
        const float bias = bl[col];
#pragma unroll
        for (int r = 0; r < 4; r++) {
            const int row = r0 + kgrp * 4 + r;
            if (row < N_NODES) {
                float v = fmaxf(acc[c][r] + bias, 0.0f);
                if (STORE_F32)
                    ((float*)outp)[(size_t)row * HID + col] = v;
                else
                    ((bf16*)outp)[(size_t)row * HID + col] = __float2bfloat16(v);
            }
        }
    }
}

extern "C" void kernel_launch(void* const* d_in, const int* in_sizes, int n_in,
                              void* d_out, int out_size, void* d_ws, size_t ws_size,
                              hipStream_t stream) {
    const float* x     = (const float*)d_in[0];
    const int*   ei    = (const int*)d_in[1];
    const float* emb_W = (const float*)d_in[2];
    const float* emb_b = (const float*)d_in[3];
    const float* Wl    = (const float*)d_in[4];
    const float* bl    = (const float*)d_in[5];
    const float* Wr    = (const float*)d_in[6];

    const int* src = ei;
    const int* dst = ei + N_EDGES;

    // workspace layout
    char* ws = (char*)d_ws;
    size_t o = 0;
    int*  degbuf = (int*)(ws + o);  o += ((size_t)N_NODES * 4 + 255) & ~(size_t)255;
    int*  rowcur = (int*)(ws + o);  o += ((size_t)N_NODES * 4 + 255) & ~(size_t)255;
    int*  csrsrc = (int*)(ws + o);  o += ((size_t)N_EDGES * 4 + 255) & ~(size_t)255;
    int*  bsum   = (int*)(ws + o);  o += ((size_t)NCH * 4 + 255) & ~(size_t)255;
    int*  boff   = (int*)(ws + o);  o += ((size_t)NCH * 4 + 255) & ~(size_t)255;
    bf16* WlT    = (bf16*)(ws + o); o += ((size_t)NLAYERS * HID * HID * 2 + 255) & ~(size_t)255;
    bf16* WrT    = (bf16*)(ws + o); o += ((size_t)NLAYERS * HID * HID * 2 + 255) & ~(size_t)255;
    bf16* embT   = (bf16*)(ws + o); o += ((size_t)HID * KPAD * 2 + 255) & ~(size_t)255;
    bf16* bufA   = (bf16*)(ws + o); o += ((size_t)N_NODES * HID * 2 + 255) & ~(size_t)255;
    bf16* bufB   = (bf16*)(ws + o);

    // ---- build CSR ----
    hipMemsetAsync(degbuf, 0, (size_t)N_NODES * sizeof(int), stream);
    k_deg<<<1024, 256, 0, stream>>>(dst, degbuf);
    k_scan1<<<NCH, SB, 0, stream>>>(degbuf, bsum);
    k_scan2<<<1, SB, 0, stream>>>(bsum, boff);
    k_scan3<<<NCH, SB, 0, stream>>>(degbuf, boff, rowcur);
    k_invdeg<<<(N_NODES + 255) / 256, 256, 0, stream>>>(degbuf);
    const float* invdeg = (const float*)degbuf;
    k_fill<<<1024, 256, 0, stream>>>(src, dst, rowcur, csrsrc);
    // rowcur[n] is now the END offset of row n

    // ---- weight prep ----
    k_wconv<<<(NLAYERS * HID * HID + 255) / 256, 256, 0, stream>>>(Wl, Wr, WlT, WrT);
    k_wembT<<<(HID * KPAD + 255) / 256, 256, 0, stream>>>(emb_W, embT);

    // ---- h0 = relu(x @ emb_W + emb_b) -> bufA (bf16), via MFMA ----
    const int cgrid = (N_NODES + 63) / 64;   // 782
    k_embed_mfma<<<cgrid, 256, 0, stream>>>(x, embT, emb_b, bufA);

    for (int l = 0; l < NLAYERS; l++) {
        bf16* h_in = (l & 1) ? bufB : bufA;
        bf16* aggb = (l & 1) ? bufA : bufB;
        k_gather<<<(N_NODES + 3) / 4, 256, 0, stream>>>(rowcur, csrsrc, h_in, invdeg, aggb);
        const bf16* wlt = WlT + (size_t)l * HID * HID;
        const bf16* wrt = WrT + (size_t)l * HID * HID;
        const float* blp = bl + (size_t)l * HID;
        if (l == NLAYERS - 1)
            k_combine_mfma<1><<<cgrid, 256, 0, stream>>>(aggb, h_in, wlt, wrt, blp, d_out);
        else
            k_combine_mfma<0><<<cgrid, 256, 0, stream>>>(aggb, h_in, wlt, wrt, blp, aggb);
    }
}

// Round 8
// 388.584 us; speedup vs baseline: 1.2053x; 1.0197x over previous
//
#include <hip/hip_runtime.h>
#include <hip/hip_bf16.h>

#define N_NODES 50000
#define N_EDGES 625000
#define IN_DIM  300
#define KPAD    320   // IN_DIM padded to multiple of 32
#define HID     128
#define NLAYERS 4

#define SB      256                            // scan block size
#define NCH     ((N_NODES + SB - 1) / SB)      // 196 chunks

typedef __hip_bfloat16 bf16;
typedef __attribute__((ext_vector_type(8))) short short8;   // 8 bf16 = 4 VGPRs
typedef __attribute__((ext_vector_type(4))) float f32x4;

__device__ inline short f2bf(float v) {
    bf16 t = __float2bfloat16(v);
    return *reinterpret_cast<short*>(&t);
}
__device__ inline unsigned short f2bfu(float v) {
    bf16 t = __float2bfloat16(v);
    return *reinterpret_cast<unsigned short*>(&t);
}
__device__ inline float bflo(unsigned v) { return __uint_as_float((v & 0xffffu) << 16); }
__device__ inline float bfhi(unsigned v) { return __uint_as_float(v & 0xffff0000u); }

// ---------------- degree histogram (int) ----------------
__global__ void k_deg(const int* __restrict__ dst, int* __restrict__ deg) {
    int e = blockIdx.x * blockDim.x + threadIdx.x;
    if (e < N_EDGES) atomicAdd(&deg[dst[e]], 1);
}

// ---------------- hierarchical scan: deg -> exclusive prefix ----------------
__global__ void k_scan1(const int* __restrict__ deg, int* __restrict__ bsum) {
    const int i = blockIdx.x * SB + threadIdx.x;
    int v = (i < N_NODES) ? deg[i] : 0;
#pragma unroll
    for (int off = 32; off > 0; off >>= 1) v += __shfl_down(v, off);
    __shared__ int wsum[SB / 64];
    if ((threadIdx.x & 63) == 0) wsum[threadIdx.x >> 6] = v;
    __syncthreads();
    if (threadIdx.x == 0) {
        int s = 0;
#pragma unroll
        for (int w = 0; w < SB / 64; w++) s += wsum[w];
        bsum[blockIdx.x] = s;
    }
}

__global__ void k_scan2(const int* __restrict__ bsum, int* __restrict__ boff) {
    __shared__ int s[SB];
    const int t = threadIdx.x;
    int v = (t < NCH) ? bsum[t] : 0;
    s[t] = v;
    __syncthreads();
    for (int off = 1; off < SB; off <<= 1) {
        int u = (t >= off) ? s[t - off] : 0;
        __syncthreads();
        s[t] += u;
        __syncthreads();
    }
    if (t < NCH) boff[t] = s[t] - v;   // exclusive
}

__global__ void k_scan3(const int* __restrict__ deg, const int* __restrict__ boff,
                        int* __restrict__ rowcur) {
    __shared__ int s[SB];
    const int b = blockIdx.x, t = threadIdx.x;
    const int i = b * SB + t;
    int v = (i < N_NODES) ? deg[i] : 0;
    s[t] = v;
    __syncthreads();
    for (int off = 1; off < SB; off <<= 1) {
        int u = (t >= off) ? s[t - off] : 0;
        __syncthreads();
        s[t] += u;
        __syncthreads();
    }
    if (i < N_NODES) rowcur[i] = boff[b] + s[t] - v;   // exclusive
}

// ---------------- deg(int) -> 1/max(deg,1) (float, in place) ----------------
__global__ void k_invdeg(int* degbuf) {
    int i = blockIdx.x * blockDim.x + threadIdx.x;
    if (i < N_NODES) {
        int d = degbuf[i];
        float inv = 1.0f / (float)max(d, 1);
        ((float*)degbuf)[i] = inv;
    }
}

// ---------------- CSR fill ----------------
__global__ void k_fill(const int* __restrict__ src, const int* __restrict__ dst,
                       int* __restrict__ rowcur, int* __restrict__ csr_src) {
    int e = blockIdx.x * blockDim.x + threadIdx.x;
    if (e < N_EDGES) {
        int d = dst[e];
        int pos = atomicAdd(&rowcur[d], 1);
        csr_src[pos] = src[e];
    }
}

// ---------------- Wl/Wr -> W^T bf16 ----------------
__global__ void k_wconv(const float* __restrict__ Wl, const float* __restrict__ Wr,
                        bf16* __restrict__ WlT, bf16* __restrict__ WrT) {
    int idx = blockIdx.x * 256 + threadIdx.x;
    if (idx >= NLAYERS * HID * HID) return;
    int l = idx / (HID * HID);
    int rem = idx - l * HID * HID;
    int k = rem >> 7;
    int f = rem & 127;
    size_t o = (size_t)l * HID * HID + (size_t)f * HID + k;
    WlT[o] = __float2bfloat16(Wl[idx]);
    WrT[o] = __float2bfloat16(Wr[idx]);
}

// ---------------- emb_W[300][128] -> embT[128][KPAD] bf16 (zero-padded K) ----------------
__global__ void k_wembT(const float* __restrict__ W, bf16* __restrict__ embT) {
    int idx = blockIdx.x * 256 + threadIdx.x;
    if (idx >= HID * KPAD) return;
    int f = idx / KPAD, k = idx - f * KPAD;
    float v = (k < IN_DIM) ? W[(size_t)k * HID + f] : 0.0f;
    embT[idx] = __float2bfloat16(v);
}

// ---------------- embedding via MFMA, K-split for 2x TLP ----------------
// block = 256 thr = 4 waves = 2 row-tiles x 2 K-halves; 32 rows/block; grid 1563
// kh=0: kk 0..4, kh=1: kk 5..9 (kk=9 masked). LDS reduce of the two halves.
__global__ void k_embed_mfma(const float* __restrict__ x, const bf16* __restrict__ embT,
                             const float* __restrict__ b, bf16* __restrict__ h) {
    __shared__ f32x4 red[2][8][64];          // 16 KB
    const int wid  = threadIdx.x >> 6;
    const int lane = threadIdx.x & 63;
    const int rt   = wid >> 1;               // row-tile 0/1
    const int kh   = wid & 1;                // K-half 0/1
    const int r0   = blockIdx.x * 32 + rt * 16;
    const int lrow = lane & 15;
    const int kgrp = lane >> 4;

    const int arow = min(r0 + lrow, N_NODES - 1);
    const float* xrow = x + (size_t)arow * IN_DIM;

    f32x4 acc[8];
#pragma unroll
    for (int c = 0; c < 8; c++) acc[c] = (f32x4){0.f, 0.f, 0.f, 0.f};

    const int kkbeg = kh * 5;
#pragma unroll
    for (int kk = kkbeg; kk < kkbeg + 5; kk++) {
        const int k0 = kk * 32 + kgrp * 8;
        short8 a;
        if (kk < 9) {                        // all 8 floats valid (max k = 288 <= 300-8)
            float4 f0 = *reinterpret_cast<const float4*>(xrow + k0);
            float4 f1 = *reinterpret_cast<const float4*>(xrow + k0 + 4);
            a[0] = f2bf(f0.x); a[1] = f2bf(f0.y); a[2] = f2bf(f0.z); a[3] = f2bf(f0.w);
            a[4] = f2bf(f1.x); a[5] = f2bf(f1.y); a[6] = f2bf(f1.z); a[7] = f2bf(f1.w);
        } else {                             // kk=9: k in [288,320), valid < 300
#pragma unroll
            for (int j = 0; j < 8; j++) {
                int k = k0 + j;
                a[j] = f2bf((k < IN_DIM) ? xrow[k] : 0.0f);
            }
        }
#pragma unroll
        for (int c = 0; c < 8; c++) {
            short8 bfrag = *reinterpret_cast<const short8*>(embT + (size_t)(c * 16 + lrow) * KPAD + k0);
            acc[c] = __builtin_amdgcn_mfma_f32_16x16x32_bf16(a, bfrag, acc[c], 0, 0, 0);
        }
    }

    if (kh == 1) {
#pragma unroll
        for (int c = 0; c < 8; c++) red[rt][c][lane] = acc[c];
    }
    __syncthreads();
    if (kh == 0) {
#pragma unroll
        for (int c = 0; c < 8; c++) {
            f32x4 r = red[rt][c][lane];
            const int col = c * 16 + lrow;
            const float bias = b[col];
#pragma unroll
            for (int q = 0; q < 4; q++) {
                const int row = r0 + kgrp * 4 + q;
                if (row < N_NODES)
                    h[(size_t)row * HID + col] =
                        __float2bfloat16(fmaxf(acc[c][q] + r[q] + bias, 0.0f));
            }
        }
    }
}

// ---------------- gather-aggregate: quarter-wave per edge, 16B/lane, 4-deep ----------------
__global__ void k_gather(const int* __restrict__ rowend, const int* __restrict__ csr_src,
                         const bf16* __restrict__ h, const float* __restrict__ invdeg,
                         bf16* __restrict__ agg) {
    const int node = blockIdx.x * (blockDim.x >> 6) + (threadIdx.x >> 6);
    if (node >= N_NODES) return;
    const int lane = threadIdx.x & 63;
    const int g    = lane >> 4;
    const int fl   = lane & 15;
    const int beg = (node == 0) ? 0 : rowend[node - 1];
    const int end = rowend[node];

    float a0 = 0.f, a1 = 0.f, a2 = 0.f, a3 = 0.f;
    float a4 = 0.f, a5 = 0.f, a6 = 0.f, a7 = 0.f;
    float c0 = 0.f, c1 = 0.f, c2 = 0.f, c3 = 0.f;
    float c4 = 0.f, c5 = 0.f, c6 = 0.f, c7 = 0.f;

    int e = beg;
    for (; e + 16 <= end; e += 16) {        // 16 edges in flight per wave
        int s0 = csr_src[e + g];
        int s1 = csr_src[e + 4 + g];
        int s2 = csr_src[e + 8 + g];
        int s3 = csr_src[e + 12 + g];
        uint4 v0 = *reinterpret_cast<const uint4*>(h + (size_t)s0 * HID + fl * 8);
        uint4 v1 = *reinterpret_cast<const uint4*>(h + (size_t)s1 * HID + fl * 8);
        uint4 v2 = *reinterpret_cast<const uint4*>(h + (size_t)s2 * HID + fl * 8);
        uint4 v3 = *reinterpret_cast<const uint4*>(h + (size_t)s3 * HID + fl * 8);
        a0 += bflo(v0.x); a1 += bfhi(v0.x); a2 += bflo(v0.y); a3 += bfhi(v0.y);
        a4 += bflo(v0.z); a5 += bfhi(v0.z); a6 += bflo(v0.w); a7 += bfhi(v0.w);
        c0 += bflo(v1.x); c1 += bfhi(v1.x); c2 += bflo(v1.y); c3 += bfhi(v1.y);
        c4 += bflo(v1.z); c5 += bfhi(v1.z); c6 += bflo(v1.w); c7 += bfhi(v1.w);
        a0 += bflo(v2.x); a1 += bfhi(v2.x); a2 += bflo(v2.y); a3 += bfhi(v2.y);
        a4 += bflo(v2.z); a5 += bfhi(v2.z); a6 += bflo(v2.w); a7 += bfhi(v2.w);
        c0 += bflo(v3.x); c1 += bfhi(v3.x); c2 += bflo(v3.y); c3 += bfhi(v3.y);
        c4 += bflo(v3.z); c5 += bfhi(v3.z); c6 += bflo(v3.w); c7 += bfhi(v3.w);
    }
    for (; e + 8 <= end; e += 8) {
        int s0 = csr_src[e + g];
        int s1 = csr_src[e + 4 + g];
        uint4 v0 = *reinterpret_cast<const uint4*>(h + (size_t)s0 * HID + fl * 8);
        uint4 v1 = *reinterpret_cast<const uint4*>(h + (size_t)s1 * HID + fl * 8);
        a0 += bflo(v0.x); a1 += bfhi(v0.x); a2 += bflo(v0.y); a3 += bfhi(v0.y);
        a4 += bflo(v0.z); a5 += bfhi(v0.z); a6 += bflo(v0.w); a7 += bfhi(v0.w);
        c0 += bflo(v1.x); c1 += bfhi(v1.x); c2 += bflo(v1.y); c3 += bfhi(v1.y);
        c4 += bflo(v1.z); c5 += bfhi(v1.z); c6 += bflo(v1.w); c7 += bfhi(v1.w);
    }
    for (; e + 4 <= end; e += 4) {
        int s0 = csr_src[e + g];
        uint4 v0 = *reinterpret_cast<const uint4*>(h + (size_t)s0 * HID + fl * 8);
        a0 += bflo(v0.x); a1 += bfhi(v0.x); a2 += bflo(v0.y); a3 += bfhi(v0.y);
        a4 += bflo(v0.z); a5 += bfhi(v0.z); a6 += bflo(v0.w); a7 += bfhi(v0.w);
    }
    if (e < end) {                           // tail: 1..3 edges, per-group predicated
        int idx = e + g;
        bool valid = idx < end;
        int s = csr_src[valid ? idx : end - 1];
        uint4 v = *reinterpret_cast<const uint4*>(h + (size_t)s * HID + fl * 8);
        if (valid) {
            a0 += bflo(v.x); a1 += bfhi(v.x); a2 += bflo(v.y); a3 += bfhi(v.y);
            a4 += bflo(v.z); a5 += bfhi(v.z); a6 += bflo(v.w); a7 += bfhi(v.w);
        }
    }
    a0 += c0; a1 += c1; a2 += c2; a3 += c3;
    a4 += c4; a5 += c5; a6 += c6; a7 += c7;

    // reduce across the 4 groups (lanes differing in bits 4,5)
    a0 += __shfl_xor(a0, 16); a1 += __shfl_xor(a1, 16);
    a2 += __shfl_xor(a2, 16); a3 += __shfl_xor(a3, 16);
    a4 += __shfl_xor(a4, 16); a5 += __shfl_xor(a5, 16);
    a6 += __shfl_xor(a6, 16); a7 += __shfl_xor(a7, 16);
    a0 += __shfl_xor(a0, 32); a1 += __shfl_xor(a1, 32);
    a2 += __shfl_xor(a2, 32); a3 += __shfl_xor(a3, 32);
    a4 += __shfl_xor(a4, 32); a5 += __shfl_xor(a5, 32);
    a6 += __shfl_xor(a6, 32); a7 += __shfl_xor(a7, 32);

    if (g == 0) {
        const float id = invdeg[node];
        uint4 o;
        o.x = (unsigned)f2bfu(a0 * id) | ((unsigned)f2bfu(a1 * id) << 16);
        o.y = (unsigned)f2bfu(a2 * id) | ((unsigned)f2bfu(a3 * id) << 16);
        o.z = (unsigned)f2bfu(a4 * id) | ((unsigned)f2bfu(a5 * id) << 16);
        o.w = (unsigned)f2bfu(a6 * id) | ((unsigned)f2bfu(a7 * id) << 16);
        *reinterpret_cast<uint4*>(agg + (size_t)node * HID + fl * 8) = o;
    }
}

// ---------------- combine via MFMA: out = relu(agg @ Wl + bl + h_in @ Wr) ----------------
// h_out may alias agg: each wave reads only its own 16 rows before writing them.
template<int STORE_F32>
__global__ void k_combine_mfma(const bf16* __restrict__ agg, const bf16* __restrict__ h_in,
                               const bf16* __restrict__ WlT, const bf16* __restrict__ WrT,
                               const float* __restrict__ bl, void* __restrict__ outp) {
    const int wid  = threadIdx.x >> 6;
    const int lane = threadIdx.x & 63;
    const int r0   = blockIdx.x * 64 + wid * 16;
    const int lrow = lane & 15;
    const int kgrp = lane >> 4;

    f32x4 acc[8];
#pragma unroll
    for (int c = 0; c < 8; c++) acc[c] = (f32x4){0.f, 0.f, 0.f, 0.f};

    const int arow = min(r0 + lrow, N_NODES - 1);

#pragma unroll
    for (int m = 0; m < 2; m++) {
        const bf16* A  = m ? h_in : agg;
        const bf16* BT = m ? WrT  : WlT;
#pragma unroll
        for (int kk = 0; kk < 4; kk++) {
            const int k0 = kk * 32 + kgrp * 8;
            short8 a = *reinterpret_cast<const short8*>(A + (size_t)arow * HID + k0);
#pragma unroll
            for (int c = 0; c < 8; c++) {
                short8 b = *reinterpret_cast<const short8*>(BT + (size_t)(c * 16 + lrow) * HID + k0);
                acc[c] = __builtin_amdgcn_mfma_f32_16x16x32_bf16(a, b, acc[c], 0, 0, 0);
            }
        }
    }

#pragma unroll
    for (int c = 0; c < 8; c++) {
        const int col = c * 16 + lrow;
        const float bias = bl[col];
#pragma unroll
        for (int r = 0; r < 4; r++) {
            const int row = r0 + kgrp * 4 + r;
            if (row < N_NODES) {
                float v = fmaxf(acc[c][r] + bias, 0.0f);
                if (STORE_F32)
                    ((float*)outp)[(size_t)row * HID + col] = v;
                else
                    ((bf16*)outp)[(size_t)row * HID + col] = __float2bfloat16(v);
            }
        }
    }
}

extern "C" void kernel_launch(void* const* d_in, const int* in_sizes, int n_in,
                              void* d_out, int out_size, void* d_ws, size_t ws_size,
                              hipStream_t stream) {
    const float* x     = (const float*)d_in[0];
    const int*   ei    = (const int*)d_in[1];
    const float* emb_W = (const float*)d_in[2];
    const float* emb_b = (const float*)d_in[3];
    const float* Wl    = (const float*)d_in[4];
    const float* bl    = (const float*)d_in[5];
    const float* Wr    = (const float*)d_in[6];

    const int* src = ei;
    const int* dst = ei + N_EDGES;

    // workspace layout
    char* ws = (char*)d_ws;
    size_t o = 0;
    int*  degbuf = (int*)(ws + o);  o += ((size_t)N_NODES * 4 + 255) & ~(size_t)255;
    int*  rowcur = (int*)(ws + o);  o += ((size_t)N_NODES * 4 + 255) & ~(size_t)255;
    int*  csrsrc = (int*)(ws + o);  o += ((size_t)N_EDGES * 4 + 255) & ~(size_t)255;
    int*  bsum   = (int*)(ws + o);  o += ((size_t)NCH * 4 + 255) & ~(size_t)255;
    int*  boff   = (int*)(ws + o);  o += ((size_t)NCH * 4 + 255) & ~(size_t)255;
    bf16* WlT    = (bf16*)(ws + o); o += ((size_t)NLAYERS * HID * HID * 2 + 255) & ~(size_t)255;
    bf16* WrT    = (bf16*)(ws + o); o += ((size_t)NLAYERS * HID * HID * 2 + 255) & ~(size_t)255;
    bf16* embT   = (bf16*)(ws + o); o += ((size_t)HID * KPAD * 2 + 255) & ~(size_t)255;
    bf16* bufA   = (bf16*)(ws + o); o += ((size_t)N_NODES * HID * 2 + 255) & ~(size_t)255;
    bf16* bufB   = (bf16*)(ws + o);

    // ---- build CSR ----
    hipMemsetAsync(degbuf, 0, (size_t)N_NODES * sizeof(int), stream);
    k_deg<<<(N_EDGES + 255) / 256, 256, 0, stream>>>(dst, degbuf);
    k_scan1<<<NCH, SB, 0, stream>>>(degbuf, bsum);
    k_scan2<<<1, SB, 0, stream>>>(bsum, boff);
    k_scan3<<<NCH, SB, 0, stream>>>(degbuf, boff, rowcur);
    k_invdeg<<<(N_NODES + 255) / 256, 256, 0, stream>>>(degbuf);
    const float* invdeg = (const float*)degbuf;
    k_fill<<<(N_EDGES + 255) / 256, 256, 0, stream>>>(src, dst, rowcur, csrsrc);
    // rowcur[n] is now the END offset of row n

    // ---- weight prep ----
    k_wconv<<<(NLAYERS * HID * HID + 255) / 256, 256, 0, stream>>>(Wl, Wr, WlT, WrT);
    k_wembT<<<(HID * KPAD + 255) / 256, 256, 0, stream>>>(emb_W, embT);

    // ---- h0 = relu(x @ emb_W + emb_b) -> bufA (bf16), via MFMA (K-split) ----
    k_embed_mfma<<<(N_NODES + 31) / 32, 256, 0, stream>>>(x, embT, emb_b, bufA);

    const int cgrid = (N_NODES + 63) / 64;   // 782
    for (int l = 0; l < NLAYERS; l++) {
        bf16* h_in = (l & 1) ? bufB : bufA;
        bf16* aggb = (l & 1) ? bufA : bufB;
        k_gather<<<(N_NODES + 3) / 4, 256, 0, stream>>>(rowcur, csrsrc, h_in, invdeg, aggb);
        const bf16* wlt = WlT + (size_t)l * HID * HID;
        const bf16* wrt = WrT + (size_t)l * HID * HID;
        const float* blp = bl + (size_t)l * HID;
        if (l == NLAYERS - 1)
            k_combine_mfma<1><<<cgrid, 256, 0, stream>>>(aggb, h_in, wlt, wrt, blp, d_out);
        else
            k_combine_mfma<0><<<cgrid, 256, 0, stream>>>(aggb, h_in, wlt, wrt, blp, aggb);
    }
}